// Round 5
// baseline (294.211 us; speedup 1.0000x reference)
//
#include <hip/hip_runtime.h>
#include <math.h>

// ---------------------------------------------------------------------------
// HierarchicalVAE, MI355X (gfx950), fp32. One block per batch row (128 x 1024
// threads), full pipeline per block, all intermediates in LDS, no barriers.
// Round-5: Round-4 was memory-LATENCY bound (VALUBusy 6%, HBM 4%; ~150us of
// L2-hit stall on scalar 4-B weight streams). Fix: float4 weight loads +
// 16 waves/block + split-K so per-thread serial load chains shrink ~8x.
//
// Output layout (flat f32): rendered@0, mu@100352, logvar@108544,
// cp@116736, widths@124928, alphas@125184.
// ---------------------------------------------------------------------------

#define O_MU  100352
#define O_LV  108544
#define O_CP  116736
#define O_WD  124928
#define O_AL  125184

__device__ __forceinline__ float leaky(float x) {
    return x >= 0.0f ? x : 0.2f * x;
}
__device__ __forceinline__ float selu(float x) {
    const float scale = 1.0507009873554805f;
    const float alpha = 1.6732632423543772f;
    return x > 0.0f ? scale * x : scale * (alpha * expm1f(x));
}
__device__ __forceinline__ void fma4(float4& acc, float a, const float4 w) {
    acc.x = fmaf(a, w.x, acc.x);
    acc.y = fmaf(a, w.y, acc.y);
    acc.z = fmaf(a, w.z, acc.z);
    acc.w = fmaf(a, w.w, acc.w);
}
__device__ __forceinline__ void add4(float4& a, const float4 b) {
    a.x += b.x; a.y += b.y; a.z += b.z; a.w += b.w;
}

__global__ __launch_bounds__(1024)
void pipeline(const float* __restrict__ x, const float* __restrict__ eps,
              const float* __restrict__ enc_w1, const float* __restrict__ enc_b1,
              const float* __restrict__ enc_w2, const float* __restrict__ enc_b2,
              const float* __restrict__ mu_w, const float* __restrict__ mu_b,
              const float* __restrict__ lv_w, const float* __restrict__ lv_b,
              const float* __restrict__ dec_w1, const float* __restrict__ dec_b1,
              const float* __restrict__ dec_w2, const float* __restrict__ dec_b2,
              const float* __restrict__ cp_w, const float* __restrict__ cp_b,
              const float* __restrict__ ref_w1, const float* __restrict__ ref_b1,
              const float* __restrict__ ref_w2, const float* __restrict__ ref_b2,
              const float* __restrict__ wd_w, const float* __restrict__ wd_b,
              const float* __restrict__ al_w, const float* __restrict__ al_b,
              float* __restrict__ out) {
    __shared__ float  sX[784];     // input row
    __shared__ float4 sPart4[1024];// split-K float4 partials (16 KB)
    __shared__ float  sH1[256];    // enc1 out
    __shared__ float  sHe[256];    // enc2 out
    __shared__ float  sML[128];    // mu | lv
    __shared__ float  sIn[96];     // h_in: z(64) | pts_norm(28)
    __shared__ float  sD1[512];    // dec1 out
    __shared__ float  sH2[512];    // dec2 out
    __shared__ float  sR1[512];    // ref1 out
    __shared__ float  sP[56];      // points (52)
    __shared__ float  sQ[128];     // polyline [p*64 + m*2 + d]
    __shared__ float  sWA[4];      // w0 w1 a0 a1

    const int row = blockIdx.x;
    const int tid = threadIdx.x;

    if (tid < 784) sX[tid] = x[row * 784 + tid];
    __syncthreads();

    // ---- enc1: 784 -> 256, leaky. jv=tid&63 (64 float4 cols), g=tid>>6 (16), K-slice 49.
    {
        const int jv = tid & 63, g = tid >> 6;
        const float4* __restrict__ W4 = (const float4*)enc_w1;
        const int k0 = g * 49;
        float4 acc = {0.f, 0.f, 0.f, 0.f};
#pragma unroll 7
        for (int i = 0; i < 49; i++) {
            fma4(acc, sX[k0 + i], W4[(k0 + i) * 64 + jv]);
        }
        sPart4[g * 64 + jv] = acc;
    }
    __syncthreads();
    if (tid < 64) {
        float4 s = ((const float4*)enc_b1)[tid];
#pragma unroll
        for (int g = 0; g < 16; g++) add4(s, sPart4[g * 64 + tid]);
        s.x = leaky(s.x); s.y = leaky(s.y); s.z = leaky(s.z); s.w = leaky(s.w);
        ((float4*)sH1)[tid] = s;
    }
    __syncthreads();

    // ---- enc2: 256 -> 256, leaky. jv 64, g 16, K-slice 16.
    {
        const int jv = tid & 63, g = tid >> 6;
        const float4* __restrict__ W4 = (const float4*)enc_w2;
        const int k0 = g * 16;
        float4 acc = {0.f, 0.f, 0.f, 0.f};
#pragma unroll
        for (int i = 0; i < 16; i++) {
            fma4(acc, sH1[k0 + i], W4[(k0 + i) * 64 + jv]);
        }
        sPart4[g * 64 + jv] = acc;
    }
    __syncthreads();
    if (tid < 64) {
        float4 s = ((const float4*)enc_b2)[tid];
#pragma unroll
        for (int g = 0; g < 16; g++) add4(s, sPart4[g * 64 + tid]);
        s.x = leaky(s.x); s.y = leaky(s.y); s.z = leaky(s.z); s.w = leaky(s.w);
        ((float4*)sHe)[tid] = s;
    }
    __syncthreads();

    // ---- mu / logvar: 128 outputs x 8 lanes, K=256.
    {
        const int o = tid >> 3, g = tid & 7;
        const int j = o & 63;
        const bool is_lv = o >= 64;
        const float* __restrict__ W = is_lv ? lv_w : mu_w;
        float acc = 0.f;
        for (int k = g; k < 256; k += 8) acc = fmaf(sHe[k], W[k * 64 + j], acc);
        acc += __shfl_xor(acc, 1);
        acc += __shfl_xor(acc, 2);
        acc += __shfl_xor(acc, 4);
        if (g == 0) {
            acc += is_lv ? lv_b[j] : mu_b[j];
            out[(is_lv ? O_LV : O_MU) + row * 64 + j] = acc;
            sML[o] = acc;
        }
    }
    __syncthreads();
    if (tid < 64)
        sIn[tid] = fmaf(eps[row * 64 + tid], expf(0.5f * sML[64 + tid]), sML[tid]);
    __syncthreads();

    // ---- dec1: 64 -> 512, selu. jv=tid&127 (128 float4 cols), g=tid>>7 (8), K-slice 8.
    {
        const int jv = tid & 127, g = tid >> 7;
        const float4* __restrict__ W4 = (const float4*)dec_w1;
        const int k0 = g * 8;
        float4 acc = {0.f, 0.f, 0.f, 0.f};
#pragma unroll
        for (int i = 0; i < 8; i++) {
            fma4(acc, sIn[k0 + i], W4[(k0 + i) * 128 + jv]);
        }
        sPart4[g * 128 + jv] = acc;
    }
    __syncthreads();
    if (tid < 128) {
        float4 s = ((const float4*)dec_b1)[tid];
#pragma unroll
        for (int g = 0; g < 8; g++) add4(s, sPart4[g * 128 + tid]);
        s.x = selu(s.x); s.y = selu(s.y); s.z = selu(s.z); s.w = selu(s.w);
        ((float4*)sD1)[tid] = s;
    }
    __syncthreads();

    // ---- dec2: 512 -> 512, selu. jv 128, g 8, K-slice 64.
    {
        const int jv = tid & 127, g = tid >> 7;
        const float4* __restrict__ W4 = (const float4*)dec_w2;
        const int k0 = g * 64;
        float4 acc = {0.f, 0.f, 0.f, 0.f};
#pragma unroll 8
        for (int i = 0; i < 64; i++) {
            fma4(acc, sD1[k0 + i], W4[(k0 + i) * 128 + jv]);
        }
        sPart4[g * 128 + jv] = acc;
    }
    __syncthreads();
    if (tid < 128) {
        float4 s = ((const float4*)dec_b2)[tid];
#pragma unroll
        for (int g = 0; g < 8; g++) add4(s, sPart4[g * 128 + tid]);
        s.x = selu(s.x); s.y = selu(s.y); s.z = selu(s.z); s.w = selu(s.w);
        ((float4*)sH2)[tid] = s;
    }
    __syncthreads();

    // ---- heads: 32 outputs x 32 lanes, K=512.
    {
        const int o = tid >> 5, g = tid & 31;
        const float* __restrict__ W;
        int ldw, col;
        if (o < 28)      { W = cp_w; ldw = 28; col = o; }
        else if (o < 30) { W = wd_w; ldw = 2;  col = o - 28; }
        else             { W = al_w; ldw = 2;  col = o - 30; }
        float acc = 0.f;
        for (int k = g; k < 512; k += 32) acc = fmaf(sH2[k], W[k * ldw + col], acc);
        acc += __shfl_xor(acc, 1);
        acc += __shfl_xor(acc, 2);
        acc += __shfl_xor(acc, 4);
        acc += __shfl_xor(acc, 8);
        acc += __shfl_xor(acc, 16);
        if (g == 0) {
            if (o < 28) {
                sIn[64 + o] = tanhf(acc + cp_b[col]);          // pts_norm
            } else if (o < 30) {
                float v = 1.f / (1.f + expf(-(acc + wd_b[col])));
                v = fmaf(v, 2.f, 1.f);
                out[O_WD + row * 2 + col] = v;
                sWA[col] = v;
            } else {
                float v = 1.f / (1.f + expf(-(acc + al_b[col])));
                out[O_AL + row * 2 + col] = v;
                sWA[2 + col] = v;
            }
        }
    }
    __syncthreads();

    // ---- ref1: 92 -> 512, selu. jv 128, g 8, K-slice 12 (last group 8).
    {
        const int jv = tid & 127, g = tid >> 7;
        const float4* __restrict__ W4 = (const float4*)ref_w1;
        const int k0 = g * 12;
        const int kend = (k0 + 12 < 92) ? (k0 + 12) : 92;
        float4 acc = {0.f, 0.f, 0.f, 0.f};
        for (int k = k0; k < kend; k++) {
            fma4(acc, sIn[k], W4[k * 128 + jv]);
        }
        sPart4[g * 128 + jv] = acc;
    }
    __syncthreads();
    if (tid < 128) {
        float4 s = ((const float4*)ref_b1)[tid];
#pragma unroll
        for (int g = 0; g < 8; g++) add4(s, sPart4[g * 128 + tid]);
        s.x = selu(s.x); s.y = selu(s.y); s.z = selu(s.z); s.w = selu(s.w);
        ((float4*)sR1)[tid] = s;
    }
    __syncthreads();

    // ---- ref2: 52 outputs x 16 lanes, K=512 -> points.
    {
        const int o = tid >> 4, g = tid & 15;
        float acc = 0.f;
        if (o < 52)
            for (int k = g; k < 512; k += 16) acc = fmaf(sR1[k], ref_w2[k * 52 + o], acc);
        acc += __shfl_xor(acc, 1);
        acc += __shfl_xor(acc, 2);
        acc += __shfl_xor(acc, 4);
        acc += __shfl_xor(acc, 8);
        if (g == 0 && o < 52)
            sP[o] = fmaf(tanhf(acc + ref_b2[o]), 12.f, 14.f);  // *SCALE + HALF
    }
    __syncthreads();

    // ---- control_points out + bezier polyline q
    if (tid < 64) {
        int idx = tid;
        int p = idx >> 5, rest = idx & 31;
        int s = rest >> 3, kk = (rest >> 1) & 3, d = idx & 1;
        out[O_CP + row * 64 + idx] = sP[p * 26 + (3 * s + kk) * 2 + d];
    }
    if (tid < 128) {
        int idx = tid;
        int p = idx >> 6, s = (idx >> 4) & 3, ti = (idx >> 1) & 7, d = idx & 1;
        float t = (float)ti / 7.0f;
        float mt = 1.0f - t;
        float c0 = mt * mt * mt;
        float c1 = 3.f * mt * mt * t;
        float c2 = 3.f * mt * t * t;
        float c3 = t * t * t;
        const float* base = sP + p * 26 + (3 * s) * 2 + d;
        sQ[idx] = c0 * base[0] + c1 * base[2] + c2 * base[4] + c3 * base[6];
    }
    __syncthreads();

    // ---- raster: 784 px x 4 AA subsamples = 3136 units.
    const float2* __restrict__ sQ2 = (const float2*)sQ;
    for (int u = tid; u < 3136; u += 1024) {
        const int pixel = u >> 2;
        const int sub = u & 3;
        const int py = pixel / 28;
        const int px = pixel - py * 28;
        const float sy = ((float)(2 * py + (sub >> 1)) + 0.5f) * 0.5f;
        const float sx = ((float)(2 * px + (sub & 1)) + 0.5f) * 0.5f;
        float img = 1.0f;
#pragma unroll
        for (int p = 0; p < 2; p++) {
            float dmin2 = 1e30f;
            int cnt = 0;
            float2 cur = sQ2[p * 32];
            bool bp = cur.y > sy;
#pragma unroll
            for (int m = 0; m < 32; m++) {
                float2 nxt = sQ2[p * 32 + ((m + 1) & 31)];
                float dx = sx - cur.x;
                float dy = sy - cur.y;
                dmin2 = fminf(dmin2, fmaf(dx, dx, dy * dy));
                bool bn = nxt.y > sy;
                float den = nxt.y - cur.y + 1e-8f;
                float lhs = dx * den;
                float rhs = dy * (nxt.x - cur.x);
                if ((bp != bn) && ((lhs < rhs) == (den > 0.0f))) cnt++;
                cur = nxt;
                bp = bn;
            }
            float dist = sqrtf(dmin2);
            float stroke = fminf(fmaxf(fmaf(sWA[p], 0.5f, 0.5f) - dist, 0.f), 1.f);
            float cov = fmaxf((float)(cnt & 1), stroke);
            img *= fmaf(-sWA[2 + p], cov, 1.0f);
        }
        img += __shfl_xor(img, 1);
        img += __shfl_xor(img, 2);
        if (sub == 0) out[row * 784 + pixel] = 1.0f - 0.25f * img;
    }
}

extern "C" void kernel_launch(void* const* d_in, const int* in_sizes, int n_in,
                              void* d_out, int out_size, void* d_ws, size_t ws_size,
                              hipStream_t stream) {
    const float* x      = (const float*)d_in[0];
    const float* eps    = (const float*)d_in[1];
    const float* enc_w1 = (const float*)d_in[2];
    const float* enc_b1 = (const float*)d_in[3];
    const float* enc_w2 = (const float*)d_in[4];
    const float* enc_b2 = (const float*)d_in[5];
    const float* mu_w   = (const float*)d_in[6];
    const float* mu_b   = (const float*)d_in[7];
    const float* lv_w   = (const float*)d_in[8];
    const float* lv_b   = (const float*)d_in[9];
    const float* dec_w1 = (const float*)d_in[10];
    const float* dec_b1 = (const float*)d_in[11];
    const float* dec_w2 = (const float*)d_in[12];
    const float* dec_b2 = (const float*)d_in[13];
    const float* cp_w   = (const float*)d_in[14];
    const float* cp_b   = (const float*)d_in[15];
    const float* ref_w1 = (const float*)d_in[16];
    const float* ref_b1 = (const float*)d_in[17];
    const float* ref_w2 = (const float*)d_in[18];
    const float* ref_b2 = (const float*)d_in[19];
    const float* wd_w   = (const float*)d_in[20];
    const float* wd_b   = (const float*)d_in[21];
    const float* al_w   = (const float*)d_in[22];
    const float* al_b   = (const float*)d_in[23];

    float* out = (float*)d_out;

    pipeline<<<128, 1024, 0, stream>>>(x, eps, enc_w1, enc_b1, enc_w2, enc_b2,
                                       mu_w, mu_b, lv_w, lv_b, dec_w1, dec_b1,
                                       dec_w2, dec_b2, cp_w, cp_b, ref_w1, ref_b1,
                                       ref_w2, ref_b2, wd_w, wd_b, al_w, al_b,
                                       out);
}

// Round 6
// 209.779 us; speedup vs baseline: 1.4025x; 1.4025x over previous
//
#include <hip/hip_runtime.h>
#include <math.h>

// ---------------------------------------------------------------------------
// HierarchicalVAE, MI355X (gfx950), fp32. One block per batch row (128 x 512
// threads), full pipeline per block, intermediates in LDS, no grid barriers.
// R5 post-mortem: 1024 threads forced VGPR=64 -> ~270MB scratch spill traffic.
// R6: back to 512 threads (launch_bounds(512,1) -> up to 256 VGPR, no spill),
// keeping float4 weight loads + split-K LDS reduction from R5.
//
// Output layout (flat f32): rendered@0, mu@100352, logvar@108544,
// cp@116736, widths@124928, alphas@125184.
// ---------------------------------------------------------------------------

#define O_MU  100352
#define O_LV  108544
#define O_CP  116736
#define O_WD  124928
#define O_AL  125184

__device__ __forceinline__ float leaky(float x) {
    return x >= 0.0f ? x : 0.2f * x;
}
__device__ __forceinline__ float selu(float x) {
    const float scale = 1.0507009873554805f;
    const float alpha = 1.6732632423543772f;
    return x > 0.0f ? scale * x : scale * (alpha * expm1f(x));
}
__device__ __forceinline__ void fma4(float4& acc, float a, const float4 w) {
    acc.x = fmaf(a, w.x, acc.x);
    acc.y = fmaf(a, w.y, acc.y);
    acc.z = fmaf(a, w.z, acc.z);
    acc.w = fmaf(a, w.w, acc.w);
}
__device__ __forceinline__ void add4(float4& a, const float4 b) {
    a.x += b.x; a.y += b.y; a.z += b.z; a.w += b.w;
}

__global__ __launch_bounds__(512, 1)
void pipeline(const float* __restrict__ x, const float* __restrict__ eps,
              const float* __restrict__ enc_w1, const float* __restrict__ enc_b1,
              const float* __restrict__ enc_w2, const float* __restrict__ enc_b2,
              const float* __restrict__ mu_w, const float* __restrict__ mu_b,
              const float* __restrict__ lv_w, const float* __restrict__ lv_b,
              const float* __restrict__ dec_w1, const float* __restrict__ dec_b1,
              const float* __restrict__ dec_w2, const float* __restrict__ dec_b2,
              const float* __restrict__ cp_w, const float* __restrict__ cp_b,
              const float* __restrict__ ref_w1, const float* __restrict__ ref_b1,
              const float* __restrict__ ref_w2, const float* __restrict__ ref_b2,
              const float* __restrict__ wd_w, const float* __restrict__ wd_b,
              const float* __restrict__ al_w, const float* __restrict__ al_b,
              float* __restrict__ out) {
    __shared__ float  sX[784];     // input row
    __shared__ float4 sPart4[512]; // split-K float4 partials (8 KB)
    __shared__ float  sH1[256];    // enc1 out
    __shared__ float  sHe[256];    // enc2 out
    __shared__ float  sML[128];    // mu | lv
    __shared__ float  sIn[96];     // h_in: z(64) | pts_norm(28)
    __shared__ float  sD1[512];    // dec1 out
    __shared__ float  sH2[512];    // dec2 out
    __shared__ float  sR1[512];    // ref1 out
    __shared__ float  sP[56];      // points (52)
    __shared__ float  sQ[128];     // polyline [p*64 + m*2 + d]
    __shared__ float  sWA[4];      // w0 w1 a0 a1

    const int row = blockIdx.x;
    const int tid = threadIdx.x;

    for (int i = tid; i < 784; i += 512) sX[i] = x[row * 784 + i];
    __syncthreads();

    // ---- enc1: 784 -> 256 leaky. 64 float4 cols x 8 K-groups, slice 98.
    {
        const int jv = tid & 63, g = tid >> 6;
        const float4* __restrict__ W4 = (const float4*)enc_w1;
        const int k0 = g * 98;
        float4 acc0 = {0,0,0,0}, acc1 = {0,0,0,0};
#pragma unroll 7
        for (int i = 0; i < 98; i += 2) {
            fma4(acc0, sX[k0 + i + 0], W4[(k0 + i + 0) * 64 + jv]);
            fma4(acc1, sX[k0 + i + 1], W4[(k0 + i + 1) * 64 + jv]);
        }
        add4(acc0, acc1);
        sPart4[g * 64 + jv] = acc0;
    }
    __syncthreads();
    if (tid < 64) {
        float4 s = ((const float4*)enc_b1)[tid];
#pragma unroll
        for (int g = 0; g < 8; g++) add4(s, sPart4[g * 64 + tid]);
        s.x = leaky(s.x); s.y = leaky(s.y); s.z = leaky(s.z); s.w = leaky(s.w);
        ((float4*)sH1)[tid] = s;
    }
    __syncthreads();

    // ---- enc2: 256 -> 256 leaky. 64 float4 cols x 8 K-groups, slice 32.
    {
        const int jv = tid & 63, g = tid >> 6;
        const float4* __restrict__ W4 = (const float4*)enc_w2;
        const int k0 = g * 32;
        float4 acc0 = {0,0,0,0}, acc1 = {0,0,0,0};
#pragma unroll 8
        for (int i = 0; i < 32; i += 2) {
            fma4(acc0, sH1[k0 + i + 0], W4[(k0 + i + 0) * 64 + jv]);
            fma4(acc1, sH1[k0 + i + 1], W4[(k0 + i + 1) * 64 + jv]);
        }
        add4(acc0, acc1);
        sPart4[g * 64 + jv] = acc0;
    }
    __syncthreads();
    if (tid < 64) {
        float4 s = ((const float4*)enc_b2)[tid];
#pragma unroll
        for (int g = 0; g < 8; g++) add4(s, sPart4[g * 64 + tid]);
        s.x = leaky(s.x); s.y = leaky(s.y); s.z = leaky(s.z); s.w = leaky(s.w);
        ((float4*)sHe)[tid] = s;
    }
    __syncthreads();

    // ---- mu|lv: 32 float4 outputs (o4<16: mu, else lv) x 16 K-groups, slice 16.
    {
        const int o4 = tid >> 4, g = tid & 15;
        const int jv = o4 & 15;
        const float4* __restrict__ W4 = (const float4*)(o4 < 16 ? mu_w : lv_w);
        const int k0 = g * 16;
        float4 acc = {0,0,0,0};
#pragma unroll
        for (int i = 0; i < 16; i++)
            fma4(acc, sHe[k0 + i], W4[(k0 + i) * 16 + jv]);
        sPart4[o4 * 16 + g] = acc;
    }
    __syncthreads();
    if (tid < 32) {
        const int jv = tid & 15;
        float4 s = (tid < 16) ? ((const float4*)mu_b)[jv] : ((const float4*)lv_b)[jv];
#pragma unroll
        for (int g = 0; g < 16; g++) add4(s, sPart4[tid * 16 + g]);
        ((float4*)sML)[tid] = s;  // sML = mu(64) | lv(64)
        float4* o4p = (float4*)(out + (tid < 16 ? O_MU : O_LV) + row * 64);
        o4p[jv] = s;
    }
    __syncthreads();
    if (tid < 64)
        sIn[tid] = fmaf(eps[row * 64 + tid], expf(0.5f * sML[64 + tid]), sML[tid]);
    __syncthreads();

    // ---- dec1: 64 -> 512 selu. 128 float4 cols x 4 K-groups, slice 16.
    {
        const int jv = tid & 127, g = tid >> 7;
        const float4* __restrict__ W4 = (const float4*)dec_w1;
        const int k0 = g * 16;
        float4 acc = {0,0,0,0};
#pragma unroll
        for (int i = 0; i < 16; i++)
            fma4(acc, sIn[k0 + i], W4[(k0 + i) * 128 + jv]);
        sPart4[g * 128 + jv] = acc;
    }
    __syncthreads();
    if (tid < 128) {
        float4 s = ((const float4*)dec_b1)[tid];
#pragma unroll
        for (int g = 0; g < 4; g++) add4(s, sPart4[g * 128 + tid]);
        s.x = selu(s.x); s.y = selu(s.y); s.z = selu(s.z); s.w = selu(s.w);
        ((float4*)sD1)[tid] = s;
    }
    __syncthreads();

    // ---- dec2: 512 -> 512 selu. 128 float4 cols x 4 K-groups, slice 128.
    {
        const int jv = tid & 127, g = tid >> 7;
        const float4* __restrict__ W4 = (const float4*)dec_w2;
        const int k0 = g * 128;
        float4 acc0 = {0,0,0,0}, acc1 = {0,0,0,0};
        float4 acc2 = {0,0,0,0}, acc3 = {0,0,0,0};
#pragma unroll 4
        for (int i = 0; i < 128; i += 4) {
            fma4(acc0, sD1[k0 + i + 0], W4[(k0 + i + 0) * 128 + jv]);
            fma4(acc1, sD1[k0 + i + 1], W4[(k0 + i + 1) * 128 + jv]);
            fma4(acc2, sD1[k0 + i + 2], W4[(k0 + i + 2) * 128 + jv]);
            fma4(acc3, sD1[k0 + i + 3], W4[(k0 + i + 3) * 128 + jv]);
        }
        add4(acc0, acc1); add4(acc2, acc3); add4(acc0, acc2);
        sPart4[g * 128 + jv] = acc0;
    }
    __syncthreads();
    if (tid < 128) {
        float4 s = ((const float4*)dec_b2)[tid];
#pragma unroll
        for (int g = 0; g < 4; g++) add4(s, sPart4[g * 128 + tid]);
        s.x = selu(s.x); s.y = selu(s.y); s.z = selu(s.z); s.w = selu(s.w);
        ((float4*)sH2)[tid] = s;
    }
    __syncthreads();

    // ---- heads: 32 outputs x 16 lanes, K=512.
    {
        const int o = tid >> 4, g = tid & 15;
        const float* __restrict__ W;
        int ldw, col;
        if (o < 28)      { W = cp_w; ldw = 28; col = o; }
        else if (o < 30) { W = wd_w; ldw = 2;  col = o - 28; }
        else             { W = al_w; ldw = 2;  col = o - 30; }
        float acc = 0.f;
        for (int k = g; k < 512; k += 16) acc = fmaf(sH2[k], W[k * ldw + col], acc);
        acc += __shfl_xor(acc, 1);
        acc += __shfl_xor(acc, 2);
        acc += __shfl_xor(acc, 4);
        acc += __shfl_xor(acc, 8);
        if (g == 0) {
            if (o < 28) {
                sIn[64 + o] = tanhf(acc + cp_b[col]);          // pts_norm
            } else if (o < 30) {
                float v = 1.f / (1.f + expf(-(acc + wd_b[col])));
                v = fmaf(v, 2.f, 1.f);
                out[O_WD + row * 2 + col] = v;
                sWA[col] = v;
            } else {
                float v = 1.f / (1.f + expf(-(acc + al_b[col])));
                out[O_AL + row * 2 + col] = v;
                sWA[2 + col] = v;
            }
        }
    }
    __syncthreads();

    // ---- ref1: 92 -> 512 selu. 128 float4 cols x 4 K-groups, slice 23.
    {
        const int jv = tid & 127, g = tid >> 7;
        const float4* __restrict__ W4 = (const float4*)ref_w1;
        const int k0 = g * 23;
        float4 acc = {0,0,0,0};
#pragma unroll
        for (int i = 0; i < 23; i++)
            fma4(acc, sIn[k0 + i], W4[(k0 + i) * 128 + jv]);
        sPart4[g * 128 + jv] = acc;
    }
    __syncthreads();
    if (tid < 128) {
        float4 s = ((const float4*)ref_b1)[tid];
#pragma unroll
        for (int g = 0; g < 4; g++) add4(s, sPart4[g * 128 + tid]);
        s.x = selu(s.x); s.y = selu(s.y); s.z = selu(s.z); s.w = selu(s.w);
        ((float4*)sR1)[tid] = s;
    }
    __syncthreads();

    // ---- ref2: 52 outputs x 8 lanes, K=512 -> points.
    {
        const int o = tid >> 3, g = tid & 7;
        float acc = 0.f;
        if (o < 52)
            for (int k = g; k < 512; k += 8) acc = fmaf(sR1[k], ref_w2[k * 52 + o], acc);
        acc += __shfl_xor(acc, 1);
        acc += __shfl_xor(acc, 2);
        acc += __shfl_xor(acc, 4);
        if (g == 0 && o < 52)
            sP[o] = fmaf(tanhf(acc + ref_b2[o]), 12.f, 14.f);  // *SCALE + HALF
    }
    __syncthreads();

    // ---- control_points out + bezier polyline q
    if (tid < 64) {
        int idx = tid;
        int p = idx >> 5, rest = idx & 31;
        int s = rest >> 3, kk = (rest >> 1) & 3, d = idx & 1;
        out[O_CP + row * 64 + idx] = sP[p * 26 + (3 * s + kk) * 2 + d];
    }
    if (tid < 128) {
        int idx = tid;
        int p = idx >> 6, s = (idx >> 4) & 3, ti = (idx >> 1) & 7, d = idx & 1;
        float t = (float)ti / 7.0f;
        float mt = 1.0f - t;
        float c0 = mt * mt * mt;
        float c1 = 3.f * mt * mt * t;
        float c2 = 3.f * mt * t * t;
        float c3 = t * t * t;
        const float* base = sP + p * 26 + (3 * s) * 2 + d;
        sQ[idx] = c0 * base[0] + c1 * base[2] + c2 * base[4] + c3 * base[6];
    }
    __syncthreads();

    // ---- raster: 784 px x 4 AA subsamples = 3136 units.
    const float2* __restrict__ sQ2 = (const float2*)sQ;
    for (int u = tid; u < 3136; u += 512) {
        const int pixel = u >> 2;
        const int sub = u & 3;
        const int py = pixel / 28;
        const int px = pixel - py * 28;
        const float sy = ((float)(2 * py + (sub >> 1)) + 0.5f) * 0.5f;
        const float sx = ((float)(2 * px + (sub & 1)) + 0.5f) * 0.5f;
        float img = 1.0f;
#pragma unroll
        for (int p = 0; p < 2; p++) {
            float dmin2 = 1e30f;
            int cnt = 0;
            float2 cur = sQ2[p * 32];
            bool bp = cur.y > sy;
#pragma unroll
            for (int m = 0; m < 32; m++) {
                float2 nxt = sQ2[p * 32 + ((m + 1) & 31)];
                float dx = sx - cur.x;
                float dy = sy - cur.y;
                dmin2 = fminf(dmin2, fmaf(dx, dx, dy * dy));
                bool bn = nxt.y > sy;
                float den = nxt.y - cur.y + 1e-8f;
                float lhs = dx * den;
                float rhs = dy * (nxt.x - cur.x);
                if ((bp != bn) && ((lhs < rhs) == (den > 0.0f))) cnt++;
                cur = nxt;
                bp = bn;
            }
            float dist = sqrtf(dmin2);
            float stroke = fminf(fmaxf(fmaf(sWA[p], 0.5f, 0.5f) - dist, 0.f), 1.f);
            float cov = fmaxf((float)(cnt & 1), stroke);
            img *= fmaf(-sWA[2 + p], cov, 1.0f);
        }
        img += __shfl_xor(img, 1);
        img += __shfl_xor(img, 2);
        if (sub == 0) out[row * 784 + pixel] = 1.0f - 0.25f * img;
    }
}

extern "C" void kernel_launch(void* const* d_in, const int* in_sizes, int n_in,
                              void* d_out, int out_size, void* d_ws, size_t ws_size,
                              hipStream_t stream) {
    const float* x      = (const float*)d_in[0];
    const float* eps    = (const float*)d_in[1];
    const float* enc_w1 = (const float*)d_in[2];
    const float* enc_b1 = (const float*)d_in[3];
    const float* enc_w2 = (const float*)d_in[4];
    const float* enc_b2 = (const float*)d_in[5];
    const float* mu_w   = (const float*)d_in[6];
    const float* mu_b   = (const float*)d_in[7];
    const float* lv_w   = (const float*)d_in[8];
    const float* lv_b   = (const float*)d_in[9];
    const float* dec_w1 = (const float*)d_in[10];
    const float* dec_b1 = (const float*)d_in[11];
    const float* dec_w2 = (const float*)d_in[12];
    const float* dec_b2 = (const float*)d_in[13];
    const float* cp_w   = (const float*)d_in[14];
    const float* cp_b   = (const float*)d_in[15];
    const float* ref_w1 = (const float*)d_in[16];
    const float* ref_b1 = (const float*)d_in[17];
    const float* ref_w2 = (const float*)d_in[18];
    const float* ref_b2 = (const float*)d_in[19];
    const float* wd_w   = (const float*)d_in[20];
    const float* wd_b   = (const float*)d_in[21];
    const float* al_w   = (const float*)d_in[22];
    const float* al_b   = (const float*)d_in[23];

    float* out = (float*)d_out;

    pipeline<<<128, 512, 0, stream>>>(x, eps, enc_w1, enc_b1, enc_w2, enc_b2,
                                      mu_w, mu_b, lv_w, lv_b, dec_w1, dec_b1,
                                      dec_w2, dec_b2, cp_w, cp_b, ref_w1, ref_b1,
                                      ref_w2, ref_b2, wd_w, wd_b, al_w, al_b,
                                      out);
}